// Round 2
// baseline (321.786 us; speedup 1.0000x reference)
//
#include <hip/hip_runtime.h>
#include <hip/hip_bf16.h>

// Problem constants: B=4, N=4096, DIM=1024; qkva = [B*N, 3*DIM]
#define SEQ_N 4096
#define BATCH 4
#define DIM 1024
#define M_ROWS (BATCH * SEQ_N)      // 16384
#define NCOLS (3 * DIM)             // 3072
#define KDIM DIM                    // 1024
#define CHUNK_L 64
#define NCHUNK (SEQ_N / CHUNK_L)    // 64
#define NCHANNEL (BATCH * DIM)      // 4096

using short8 = __attribute__((ext_vector_type(8))) short;
using f32x4  = __attribute__((ext_vector_type(4))) float;

static __device__ __forceinline__ unsigned short f2bf(float f) {
    union { float f; unsigned u; } v; v.f = f;
    unsigned r = v.u + 0x7fffu + ((v.u >> 16) & 1u);   // round-to-nearest-even
    return (unsigned short)(r >> 16);
}
static __device__ __forceinline__ float bf2f(unsigned short s) {
    union { unsigned u; float f; } v; v.u = ((unsigned)s) << 16;
    return v.f;
}

// ---------------- w fp32 -> bf16 ----------------
__global__ __launch_bounds__(256) void wconv_kernel(const float* __restrict__ in,
                                                    unsigned short* __restrict__ out,
                                                    int n4) {
    int i = blockIdx.x * 256 + threadIdx.x;
    if (i < n4) {
        float4 v = reinterpret_cast<const float4*>(in)[i];
        ushort4 o;
        o.x = f2bf(v.x); o.y = f2bf(v.y); o.z = f2bf(v.z); o.w = f2bf(v.w);
        reinterpret_cast<ushort4*>(out)[i] = o;
    }
}

// ---------------- RMSNorm (per row of 1024) -> bf16 ----------------
__global__ __launch_bounds__(256) void rmsnorm_kernel(const float* __restrict__ x,
                                                      const float* __restrict__ gamma,
                                                      unsigned short* __restrict__ h) {
    const int row = blockIdx.x;
    const int tid = threadIdx.x;
    const float4 v = reinterpret_cast<const float4*>(x + (size_t)row * DIM)[tid];
    float ss = v.x * v.x + v.y * v.y + v.z * v.z + v.w * v.w;
#pragma unroll
    for (int off = 32; off >= 1; off >>= 1) ss += __shfl_xor(ss, off, 64);
    __shared__ float red[4];
    if ((tid & 63) == 0) red[tid >> 6] = ss;
    __syncthreads();
    const float tot = red[0] + red[1] + red[2] + red[3];
    const float scale = 32.0f / fmaxf(sqrtf(tot), 1e-12f);   // sqrt(1024)=32
    const float4 g = reinterpret_cast<const float4*>(gamma)[tid];
    ushort4 o;
    o.x = f2bf(v.x * scale * g.x);
    o.y = f2bf(v.y * scale * g.y);
    o.z = f2bf(v.z * scale * g.z);
    o.w = f2bf(v.w * scale * g.w);
    reinterpret_cast<ushort4*>(h + (size_t)row * DIM)[tid] = o;
}

// ---------------- GEMM: C[m,e] = sum_k A[m,k] * B[e,k], bf16 in, bf16 out ----
// m97-style: 128x128 tile, BK=32, 4 waves (2x2 of 64x64), 16x16x32 bf16 MFMA,
// global_load_lds width-16 staging. MFMA operands SWAPPED (bf first) so each
// lane's 4 acc regs are 4 consecutive COLUMNS of one row -> ushort4 stores.
__global__ __launch_bounds__(256) void gemm_bt_kernel(const unsigned short* __restrict__ A,
                                                      const unsigned short* __restrict__ B,
                                                      unsigned short* __restrict__ C) {
    __shared__ __align__(16) unsigned short sA[128 * 32];
    __shared__ __align__(16) unsigned short sB[128 * 32];

    const int tid  = threadIdx.x;
    const int lane = tid & 63;
    const int wave = tid >> 6;
    const int row0 = blockIdx.y * 128;
    const int col0 = blockIdx.x * 128;
    const int wm = (wave >> 1) * 64;
    const int wn = (wave & 1) * 64;
    const int fr = lane & 15;   // frag row/col within 16x16
    const int kq = lane >> 4;   // k-quad (which 8 of K=32)

    const unsigned short* agp = A + (size_t)(row0 + (tid >> 2)) * KDIM + (tid & 3) * 8;
    const unsigned short* bgp = B + (size_t)(col0 + (tid >> 2)) * KDIM + (tid & 3) * 8;

    f32x4 acc[4][4] = {};

    for (int k0 = 0; k0 < KDIM; k0 += 32) {
        __builtin_amdgcn_global_load_lds(
            (const __attribute__((address_space(1))) void*)(agp),
            (__attribute__((address_space(3))) void*)(&sA[tid * 8]), 16, 0, 0);
        __builtin_amdgcn_global_load_lds(
            (const __attribute__((address_space(1))) void*)(agp + 64 * KDIM),
            (__attribute__((address_space(3))) void*)(&sA[2048 + tid * 8]), 16, 0, 0);
        __builtin_amdgcn_global_load_lds(
            (const __attribute__((address_space(1))) void*)(bgp),
            (__attribute__((address_space(3))) void*)(&sB[tid * 8]), 16, 0, 0);
        __builtin_amdgcn_global_load_lds(
            (const __attribute__((address_space(1))) void*)(bgp + 64 * KDIM),
            (__attribute__((address_space(3))) void*)(&sB[2048 + tid * 8]), 16, 0, 0);
        agp += 32; bgp += 32;
        __syncthreads();

        short8 af[4], bf[4];
#pragma unroll
        for (int i = 0; i < 4; ++i)
            af[i] = *reinterpret_cast<const short8*>(&sA[(wm + i * 16 + fr) * 32 + kq * 8]);
#pragma unroll
        for (int j = 0; j < 4; ++j)
            bf[j] = *reinterpret_cast<const short8*>(&sB[(wn + j * 16 + fr) * 32 + kq * 8]);
#pragma unroll
        for (int i = 0; i < 4; ++i)
#pragma unroll
            for (int j = 0; j < 4; ++j)
                acc[i][j] = __builtin_amdgcn_mfma_f32_16x16x32_bf16(bf[j], af[i], acc[i][j], 0, 0, 0);
        __syncthreads();
    }

    // epilogue (swapped operands): first operand (bf) index -> (lane>>4)*4+reg,
    // second operand (af) index -> lane&15.
    // row = row0+wm+i*16+fr ; cols = col0+wn+j*16+kq*4 + r (r=0..3, packed)
#pragma unroll
    for (int i = 0; i < 4; ++i) {
        const size_t rbase = (size_t)(row0 + wm + i * 16 + fr) * NCOLS;
#pragma unroll
        for (int j = 0; j < 4; ++j) {
            const int col = col0 + wn + j * 16 + kq * 4;
            ushort4 o;
            o.x = f2bf(acc[i][j][0]);
            o.y = f2bf(acc[i][j][1]);
            o.z = f2bf(acc[i][j][2]);
            o.w = f2bf(acc[i][j][3]);
            *reinterpret_cast<ushort4*>(&C[rbase + col]) = o;
        }
    }
}

// ---------------- Scan phase 1: per-chunk aggregates (A = prod a, Y = local state)
// 128 threads/block, 4 channels/thread (ushort4 loads), blockIdx.y splits DIM in 2.
__global__ __launch_bounds__(128) void chunk_agg_kernel(const unsigned short* __restrict__ qkva,
                                                        float* __restrict__ Aagg,
                                                        float* __restrict__ Yagg) {
    const int c = blockIdx.x, b = blockIdx.z;
    const int d4 = blockIdx.y * 128 + threadIdx.x;     // quad index; d = 4*d4
    const unsigned short* base = qkva + ((size_t)b * SEQ_N + c * CHUNK_L) * NCOLS;
    float s[4] = {0.f, 0.f, 0.f, 0.f};
    float A[4] = {1.f, 1.f, 1.f, 1.f};
#pragma unroll 4
    for (int n = 0; n < CHUNK_L; ++n) {
        ushort4 kv4 = reinterpret_cast<const ushort4*>(base + (size_t)n * NCOLS + DIM)[d4];
        ushort4 av4 = reinterpret_cast<const ushort4*>(base + (size_t)n * NCOLS + 2 * DIM)[d4];
        float kv[4] = {bf2f(kv4.x), bf2f(kv4.y), bf2f(kv4.z), bf2f(kv4.w)};
        float av[4] = {bf2f(av4.x), bf2f(av4.y), bf2f(av4.z), bf2f(av4.w)};
#pragma unroll
        for (int t = 0; t < 4; ++t) {
            float a = 1.f / (1.f + __expf(-av[t]));
            s[t] = a * s[t] + kv[t];
            A[t] *= a;
        }
    }
    float4 Ao, Yo;
    Ao.x = A[0]; Ao.y = A[1]; Ao.z = A[2]; Ao.w = A[3];
    Yo.x = s[0]; Yo.y = s[1]; Yo.z = s[2]; Yo.w = s[3];
    reinterpret_cast<float4*>(Aagg + c * NCHANNEL + b * DIM)[d4 & 255] = Ao;
    reinterpret_cast<float4*>(Yagg + c * NCHANNEL + b * DIM)[d4 & 255] = Yo;
}

// ---------------- Scan phase 2: sequential scan over chunk aggregates -> chunk entry state
__global__ __launch_bounds__(256) void agg_scan_kernel(const float* __restrict__ Aagg,
                                                       const float* __restrict__ Yagg,
                                                       float* __restrict__ Sin) {
    const int ch = blockIdx.x * 256 + threadIdx.x;   // 0..4095
    float s = 0.f;
#pragma unroll 4
    for (int c = 0; c < NCHUNK; ++c) {
        Sin[c * NCHANNEL + ch] = s;
        s = Aagg[c * NCHANNEL + ch] * s + Yagg[c * NCHANNEL + ch];
    }
}

// ---------------- Scan phase 3: rescan chunk with correct entry state, out = q*y
__global__ __launch_bounds__(128) void apply_kernel(const unsigned short* __restrict__ qkva,
                                                    const float* __restrict__ Sin,
                                                    float* __restrict__ out) {
    const int c = blockIdx.x, b = blockIdx.z;
    const int d4 = blockIdx.y * 128 + threadIdx.x;     // quad index; d = 4*d4
    const unsigned short* base = qkva + ((size_t)b * SEQ_N + c * CHUNK_L) * NCOLS;
    float* obase = out + ((size_t)b * SEQ_N + c * CHUNK_L) * DIM;
    float4 s4 = reinterpret_cast<const float4*>(Sin + c * NCHANNEL + b * DIM)[d4 & 255];
    float s[4] = {s4.x, s4.y, s4.z, s4.w};
#pragma unroll 4
    for (int n = 0; n < CHUNK_L; ++n) {
        ushort4 kv4 = reinterpret_cast<const ushort4*>(base + (size_t)n * NCOLS + DIM)[d4];
        ushort4 av4 = reinterpret_cast<const ushort4*>(base + (size_t)n * NCOLS + 2 * DIM)[d4];
        ushort4 q4  = reinterpret_cast<const ushort4*>(base + (size_t)n * NCOLS)[d4];
        float kv[4] = {bf2f(kv4.x), bf2f(kv4.y), bf2f(kv4.z), bf2f(kv4.w)};
        float av[4] = {bf2f(av4.x), bf2f(av4.y), bf2f(av4.z), bf2f(av4.w)};
        float q[4]  = {bf2f(q4.x),  bf2f(q4.y),  bf2f(q4.z),  bf2f(q4.w)};
        float4 o;
        {
            float a0 = 1.f / (1.f + __expf(-av[0])); s[0] = a0 * s[0] + kv[0]; o.x = q[0] * s[0];
            float a1 = 1.f / (1.f + __expf(-av[1])); s[1] = a1 * s[1] + kv[1]; o.y = q[1] * s[1];
            float a2 = 1.f / (1.f + __expf(-av[2])); s[2] = a2 * s[2] + kv[2]; o.z = q[2] * s[2];
            float a3 = 1.f / (1.f + __expf(-av[3])); s[3] = a3 * s[3] + kv[3]; o.w = q[3] * s[3];
        }
        reinterpret_cast<float4*>(obase + (size_t)n * DIM)[d4] = o;
    }
}

extern "C" void kernel_launch(void* const* d_in, const int* in_sizes, int n_in,
                              void* d_out, int out_size, void* d_ws, size_t ws_size,
                              hipStream_t stream) {
    const float* x     = (const float*)d_in[0];   // [4,4096,1024]
    const float* w     = (const float*)d_in[1];   // [3072,1024]
    const float* gamma = (const float*)d_in[2];   // [1024]
    float* out = (float*)d_out;                   // [4,4096,1024]

    char* ws = (char*)d_ws;
    // workspace layout (bytes):
    unsigned short* wb   = (unsigned short*)(ws);                         // 3072*1024*2   = 6,291,456
    unsigned short* h    = (unsigned short*)(ws + 6291456);               // 16384*1024*2  = 33,554,432
    unsigned short* qkva = (unsigned short*)(ws + 39845888);              // 16384*3072*2  = 100,663,296
    float* Aagg = (float*)(ws + 140509184);                               // 64*4096*4     = 1,048,576
    float* Yagg = (float*)(ws + 141557760);                               // 1,048,576
    float* Sin  = (float*)(ws + 142606336);                               // 1,048,576
    // total: 143,654,912 bytes

    wconv_kernel<<<(NCOLS * KDIM / 4 + 255) / 256, 256, 0, stream>>>(w, wb, NCOLS * KDIM / 4);
    rmsnorm_kernel<<<M_ROWS, 256, 0, stream>>>(x, gamma, h);
    gemm_bt_kernel<<<dim3(NCOLS / 128, M_ROWS / 128), 256, 0, stream>>>(h, wb, qkva);
    chunk_agg_kernel<<<dim3(NCHUNK, 2, BATCH), 128, 0, stream>>>(qkva, Aagg, Yagg);
    agg_scan_kernel<<<NCHANNEL / 256, 256, 0, stream>>>(Aagg, Yagg, Sin);
    apply_kernel<<<dim3(NCHUNK, 2, BATCH), 128, 0, stream>>>(qkva, Sin, out);
}

// Round 3
// 307.921 us; speedup vs baseline: 1.0450x; 1.0450x over previous
//
#include <hip/hip_runtime.h>
#include <hip/hip_bf16.h>

// Problem constants: B=4, N=4096, DIM=1024; qkva = [B*N, 3*DIM]
#define SEQ_N 4096
#define BATCH 4
#define DIM 1024
#define M_ROWS (BATCH * SEQ_N)      // 16384
#define NCOLS (3 * DIM)             // 3072
#define KDIM DIM                    // 1024
#define CHUNK_L 16
#define NCHUNK (SEQ_N / CHUNK_L)    // 256
#define NCHANNEL (BATCH * DIM)      // 4096

using short8 = __attribute__((ext_vector_type(8))) short;
using f32x4  = __attribute__((ext_vector_type(4))) float;

static __device__ __forceinline__ unsigned short f2bf(float f) {
    union { float f; unsigned u; } v; v.f = f;
    unsigned r = v.u + 0x7fffu + ((v.u >> 16) & 1u);   // round-to-nearest-even
    return (unsigned short)(r >> 16);
}
static __device__ __forceinline__ float bf2f(unsigned short s) {
    union { unsigned u; float f; } v; v.u = ((unsigned)s) << 16;
    return v.f;
}

// ---------------- w fp32 -> bf16 ----------------
__global__ __launch_bounds__(256) void wconv_kernel(const float* __restrict__ in,
                                                    unsigned short* __restrict__ out,
                                                    int n4) {
    int i = blockIdx.x * 256 + threadIdx.x;
    if (i < n4) {
        float4 v = reinterpret_cast<const float4*>(in)[i];
        ushort4 o;
        o.x = f2bf(v.x); o.y = f2bf(v.y); o.z = f2bf(v.z); o.w = f2bf(v.w);
        reinterpret_cast<ushort4*>(out)[i] = o;
    }
}

// ---------------- RMSNorm (per row of 1024) -> bf16 ----------------
__global__ __launch_bounds__(256) void rmsnorm_kernel(const float* __restrict__ x,
                                                      const float* __restrict__ gamma,
                                                      unsigned short* __restrict__ h) {
    const int row = blockIdx.x;
    const int tid = threadIdx.x;
    const float4 v = reinterpret_cast<const float4*>(x + (size_t)row * DIM)[tid];
    float ss = v.x * v.x + v.y * v.y + v.z * v.z + v.w * v.w;
#pragma unroll
    for (int off = 32; off >= 1; off >>= 1) ss += __shfl_xor(ss, off, 64);
    __shared__ float red[4];
    if ((tid & 63) == 0) red[tid >> 6] = ss;
    __syncthreads();
    const float tot = red[0] + red[1] + red[2] + red[3];
    const float scale = 32.0f / fmaxf(sqrtf(tot), 1e-12f);   // sqrt(1024)=32
    const float4 g = reinterpret_cast<const float4*>(gamma)[tid];
    ushort4 o;
    o.x = f2bf(v.x * scale * g.x);
    o.y = f2bf(v.y * scale * g.y);
    o.z = f2bf(v.z * scale * g.z);
    o.w = f2bf(v.w * scale * g.w);
    reinterpret_cast<ushort4*>(h + (size_t)row * DIM)[tid] = o;
}

// ---------------- GEMM: C[m,e] = sum_k A[m,k] * B[e,k], bf16 in, bf16 out ----
// m97-style: 128x128 tile, BK=32, 4 waves (2x2 of 64x64), 16x16x32 bf16 MFMA,
// global_load_lds width-16 staging. (Round-1 version: measured 141.7 us; the
// operand-swap/packed-store variant measured +4 us — reverted.)
__global__ __launch_bounds__(256) void gemm_bt_kernel(const unsigned short* __restrict__ A,
                                                      const unsigned short* __restrict__ B,
                                                      unsigned short* __restrict__ C) {
    __shared__ __align__(16) unsigned short sA[128 * 32];
    __shared__ __align__(16) unsigned short sB[128 * 32];

    const int tid  = threadIdx.x;
    const int lane = tid & 63;
    const int wave = tid >> 6;
    const int row0 = blockIdx.y * 128;
    const int col0 = blockIdx.x * 128;
    const int wm = (wave >> 1) * 64;
    const int wn = (wave & 1) * 64;
    const int fr = lane & 15;   // frag row/col within 16x16
    const int kq = lane >> 4;   // k-quad (which 8 of K=32)

    const unsigned short* agp = A + (size_t)(row0 + (tid >> 2)) * KDIM + (tid & 3) * 8;
    const unsigned short* bgp = B + (size_t)(col0 + (tid >> 2)) * KDIM + (tid & 3) * 8;

    f32x4 acc[4][4] = {};

    for (int k0 = 0; k0 < KDIM; k0 += 32) {
        __builtin_amdgcn_global_load_lds(
            (const __attribute__((address_space(1))) void*)(agp),
            (__attribute__((address_space(3))) void*)(&sA[tid * 8]), 16, 0, 0);
        __builtin_amdgcn_global_load_lds(
            (const __attribute__((address_space(1))) void*)(agp + 64 * KDIM),
            (__attribute__((address_space(3))) void*)(&sA[2048 + tid * 8]), 16, 0, 0);
        __builtin_amdgcn_global_load_lds(
            (const __attribute__((address_space(1))) void*)(bgp),
            (__attribute__((address_space(3))) void*)(&sB[tid * 8]), 16, 0, 0);
        __builtin_amdgcn_global_load_lds(
            (const __attribute__((address_space(1))) void*)(bgp + 64 * KDIM),
            (__attribute__((address_space(3))) void*)(&sB[2048 + tid * 8]), 16, 0, 0);
        agp += 32; bgp += 32;
        __syncthreads();

        short8 af[4], bf[4];
#pragma unroll
        for (int i = 0; i < 4; ++i)
            af[i] = *reinterpret_cast<const short8*>(&sA[(wm + i * 16 + fr) * 32 + kq * 8]);
#pragma unroll
        for (int j = 0; j < 4; ++j)
            bf[j] = *reinterpret_cast<const short8*>(&sB[(wn + j * 16 + fr) * 32 + kq * 8]);
#pragma unroll
        for (int i = 0; i < 4; ++i)
#pragma unroll
            for (int j = 0; j < 4; ++j)
                acc[i][j] = __builtin_amdgcn_mfma_f32_16x16x32_bf16(af[i], bf[j], acc[i][j], 0, 0, 0);
        __syncthreads();
    }

    // epilogue: C/D layout col=lane&15, row=(lane>>4)*4+reg
#pragma unroll
    for (int i = 0; i < 4; ++i) {
#pragma unroll
        for (int j = 0; j < 4; ++j) {
#pragma unroll
            for (int r = 0; r < 4; ++r) {
                int row = row0 + wm + i * 16 + kq * 4 + r;
                int col = col0 + wn + j * 16 + fr;
                C[(size_t)row * NCOLS + col] = f2bf(acc[i][j][r]);
            }
        }
    }
}

// ---------------- Scan phase 1: per-chunk aggregates (A = prod a, Y = local state)
// CHUNK_L=16: grid (256 chunks, 1, 4 batches) x 256 threads, 4 channels/thread
// via ushort4 loads -> 16 waves/CU AND 8-B/lane vector loads.
__global__ __launch_bounds__(256) void chunk_agg_kernel(const unsigned short* __restrict__ qkva,
                                                        float* __restrict__ Aagg,
                                                        float* __restrict__ Yagg) {
    const int c = blockIdx.x, b = blockIdx.y;
    const int d4 = threadIdx.x;                        // quad index 0..255; d = 4*d4
    const unsigned short* base = qkva + ((size_t)b * SEQ_N + c * CHUNK_L) * NCOLS;
    float s[4] = {0.f, 0.f, 0.f, 0.f};
    float A[4] = {1.f, 1.f, 1.f, 1.f};
#pragma unroll 4
    for (int n = 0; n < CHUNK_L; ++n) {
        ushort4 kv4 = reinterpret_cast<const ushort4*>(base + (size_t)n * NCOLS + DIM)[d4];
        ushort4 av4 = reinterpret_cast<const ushort4*>(base + (size_t)n * NCOLS + 2 * DIM)[d4];
        float kv[4] = {bf2f(kv4.x), bf2f(kv4.y), bf2f(kv4.z), bf2f(kv4.w)};
        float av[4] = {bf2f(av4.x), bf2f(av4.y), bf2f(av4.z), bf2f(av4.w)};
#pragma unroll
        for (int t = 0; t < 4; ++t) {
            float a = 1.f / (1.f + __expf(-av[t]));
            s[t] = a * s[t] + kv[t];
            A[t] *= a;
        }
    }
    float4 Ao, Yo;
    Ao.x = A[0]; Ao.y = A[1]; Ao.z = A[2]; Ao.w = A[3];
    Yo.x = s[0]; Yo.y = s[1]; Yo.z = s[2]; Yo.w = s[3];
    reinterpret_cast<float4*>(Aagg + (size_t)c * NCHANNEL + b * DIM)[d4] = Ao;
    reinterpret_cast<float4*>(Yagg + (size_t)c * NCHANNEL + b * DIM)[d4] = Yo;
}

// ---------------- Scan phase 2: sequential scan over chunk aggregates -> chunk entry state
// 4096 threads, 256 iters; aggregates (12 MB) are L2/LLC resident.
__global__ __launch_bounds__(256) void agg_scan_kernel(const float* __restrict__ Aagg,
                                                       const float* __restrict__ Yagg,
                                                       float* __restrict__ Sin) {
    const int ch = blockIdx.x * 256 + threadIdx.x;   // 0..4095
    float s = 0.f;
#pragma unroll 8
    for (int c = 0; c < NCHUNK; ++c) {
        Sin[(size_t)c * NCHANNEL + ch] = s;
        s = Aagg[(size_t)c * NCHANNEL + ch] * s + Yagg[(size_t)c * NCHANNEL + ch];
    }
}

// ---------------- Scan phase 3: rescan chunk with correct entry state, out = q*y
__global__ __launch_bounds__(256) void apply_kernel(const unsigned short* __restrict__ qkva,
                                                    const float* __restrict__ Sin,
                                                    float* __restrict__ out) {
    const int c = blockIdx.x, b = blockIdx.y;
    const int d4 = threadIdx.x;                        // quad index 0..255; d = 4*d4
    const unsigned short* base = qkva + ((size_t)b * SEQ_N + c * CHUNK_L) * NCOLS;
    float* obase = out + ((size_t)b * SEQ_N + c * CHUNK_L) * DIM;
    float4 s4 = reinterpret_cast<const float4*>(Sin + (size_t)c * NCHANNEL + b * DIM)[d4];
    float s[4] = {s4.x, s4.y, s4.z, s4.w};
#pragma unroll 4
    for (int n = 0; n < CHUNK_L; ++n) {
        ushort4 kv4 = reinterpret_cast<const ushort4*>(base + (size_t)n * NCOLS + DIM)[d4];
        ushort4 av4 = reinterpret_cast<const ushort4*>(base + (size_t)n * NCOLS + 2 * DIM)[d4];
        ushort4 q4  = reinterpret_cast<const ushort4*>(base + (size_t)n * NCOLS)[d4];
        float kv[4] = {bf2f(kv4.x), bf2f(kv4.y), bf2f(kv4.z), bf2f(kv4.w)};
        float av[4] = {bf2f(av4.x), bf2f(av4.y), bf2f(av4.z), bf2f(av4.w)};
        float q[4]  = {bf2f(q4.x),  bf2f(q4.y),  bf2f(q4.z),  bf2f(q4.w)};
        float4 o;
        {
            float a0 = 1.f / (1.f + __expf(-av[0])); s[0] = a0 * s[0] + kv[0]; o.x = q[0] * s[0];
            float a1 = 1.f / (1.f + __expf(-av[1])); s[1] = a1 * s[1] + kv[1]; o.y = q[1] * s[1];
            float a2 = 1.f / (1.f + __expf(-av[2])); s[2] = a2 * s[2] + kv[2]; o.z = q[2] * s[2];
            float a3 = 1.f / (1.f + __expf(-av[3])); s[3] = a3 * s[3] + kv[3]; o.w = q[3] * s[3];
        }
        reinterpret_cast<float4*>(obase + (size_t)n * DIM)[d4] = o;
    }
}

extern "C" void kernel_launch(void* const* d_in, const int* in_sizes, int n_in,
                              void* d_out, int out_size, void* d_ws, size_t ws_size,
                              hipStream_t stream) {
    const float* x     = (const float*)d_in[0];   // [4,4096,1024]
    const float* w     = (const float*)d_in[1];   // [3072,1024]
    const float* gamma = (const float*)d_in[2];   // [1024]
    float* out = (float*)d_out;                   // [4,4096,1024]

    char* ws = (char*)d_ws;
    // workspace layout (bytes):
    unsigned short* wb   = (unsigned short*)(ws);             // 3072*1024*2   = 6,291,456
    unsigned short* h    = (unsigned short*)(ws + 6291456);   // 16384*1024*2  = 33,554,432
    unsigned short* qkva = (unsigned short*)(ws + 39845888);  // 16384*3072*2  = 100,663,296
    // Aggregates (4 MB each) live inside h's region — h is dead after the GEMM.
    float* Aagg = (float*)(ws + 6291456);                     // 256*4096*4 = 4,194,304
    float* Yagg = (float*)(ws + 6291456 + 4194304);
    float* Sin  = (float*)(ws + 6291456 + 8388608);
    // total ws: 140,509,184 bytes (unchanged from round 1)

    wconv_kernel<<<(NCOLS * KDIM / 4 + 255) / 256, 256, 0, stream>>>(w, wb, NCOLS * KDIM / 4);
    rmsnorm_kernel<<<M_ROWS, 256, 0, stream>>>(x, gamma, h);
    gemm_bt_kernel<<<dim3(NCOLS / 128, M_ROWS / 128), 256, 0, stream>>>(h, wb, qkva);
    chunk_agg_kernel<<<dim3(NCHUNK, BATCH), 256, 0, stream>>>(qkva, Aagg, Yagg);
    agg_scan_kernel<<<NCHANNEL / 256, 256, 0, stream>>>(Aagg, Yagg, Sin);
    apply_kernel<<<dim3(NCHUNK, BATCH), 256, 0, stream>>>(qkva, Sin, out);
}

// Round 4
// 302.486 us; speedup vs baseline: 1.0638x; 1.0180x over previous
//
#include <hip/hip_runtime.h>
#include <hip/hip_bf16.h>

// Problem constants: B=4, N=4096, DIM=1024; qkva = [B*N, 3*DIM]
#define SEQ_N 4096
#define BATCH 4
#define DIM 1024
#define M_ROWS (BATCH * SEQ_N)      // 16384
#define NCOLS (3 * DIM)             // 3072
#define KDIM DIM                    // 1024
#define CHUNK_L 16
#define NCHUNK (SEQ_N / CHUNK_L)    // 256
#define NCHANNEL (BATCH * DIM)      // 4096

using short8 = __attribute__((ext_vector_type(8))) short;
using f32x4  = __attribute__((ext_vector_type(4))) float;

static __device__ __forceinline__ unsigned short f2bf(float f) {
    union { float f; unsigned u; } v; v.f = f;
    unsigned r = v.u + 0x7fffu + ((v.u >> 16) & 1u);   // round-to-nearest-even
    return (unsigned short)(r >> 16);
}
static __device__ __forceinline__ float bf2f(unsigned short s) {
    union { unsigned u; float f; } v; v.u = ((unsigned)s) << 16;
    return v.f;
}

// ---------------- Fused RMSNorm (wave-per-row) + w fp32->bf16 conversion ------
// blockIdx.x < 4096 : rmsnorm, 4 rows per block (one wave per row, no LDS/barrier)
// blockIdx.x >= 4096: wconv, 256 float4 -> ushort4 per block
__global__ __launch_bounds__(256) void prep_kernel(const float* __restrict__ x,
                                                   const float* __restrict__ gamma,
                                                   unsigned short* __restrict__ h,
                                                   const float* __restrict__ w,
                                                   unsigned short* __restrict__ wb) {
    if (blockIdx.x < 4096) {
        const int wave = threadIdx.x >> 6;
        const int lane = threadIdx.x & 63;
        const int row = blockIdx.x * 4 + wave;
        const float4* xr = reinterpret_cast<const float4*>(x + (size_t)row * DIM);
        const float4* gr = reinterpret_cast<const float4*>(gamma);
        float4 v[4];
        float ss = 0.f;
#pragma unroll
        for (int i = 0; i < 4; ++i) {
            v[i] = xr[i * 64 + lane];
            ss += v[i].x * v[i].x + v[i].y * v[i].y + v[i].z * v[i].z + v[i].w * v[i].w;
        }
#pragma unroll
        for (int off = 32; off >= 1; off >>= 1) ss += __shfl_xor(ss, off, 64);
        const float scale = 32.0f / fmaxf(sqrtf(ss), 1e-12f);   // sqrt(1024)=32
        ushort4* hr = reinterpret_cast<ushort4*>(h + (size_t)row * DIM);
#pragma unroll
        for (int i = 0; i < 4; ++i) {
            float4 g = gr[i * 64 + lane];
            ushort4 o;
            o.x = f2bf(v[i].x * scale * g.x);
            o.y = f2bf(v[i].y * scale * g.y);
            o.z = f2bf(v[i].z * scale * g.z);
            o.w = f2bf(v[i].w * scale * g.w);
            hr[i * 64 + lane] = o;
        }
    } else {
        const int i = (blockIdx.x - 4096) * 256 + threadIdx.x;   // < 786432
        float4 vv = reinterpret_cast<const float4*>(w)[i];
        ushort4 o;
        o.x = f2bf(vv.x); o.y = f2bf(vv.y); o.z = f2bf(vv.z); o.w = f2bf(vv.w);
        reinterpret_cast<ushort4*>(wb)[i] = o;
    }
}

// ---------------- GEMM: C[m,e] = sum_k A[m,k] * B[e,k], bf16 in, bf16 out ----
// m97-style: 128x128 tile, BK=32, 4 waves (2x2 of 64x64), 16x16x32 bf16 MFMA,
// global_load_lds width-16 staging. (Round-1 version, measured ~135-142 us;
// operand-swap/packed-store variant regressed — do not revisit.)
__global__ __launch_bounds__(256) void gemm_bt_kernel(const unsigned short* __restrict__ A,
                                                      const unsigned short* __restrict__ B,
                                                      unsigned short* __restrict__ C) {
    __shared__ __align__(16) unsigned short sA[128 * 32];
    __shared__ __align__(16) unsigned short sB[128 * 32];

    const int tid  = threadIdx.x;
    const int lane = tid & 63;
    const int wave = tid >> 6;
    const int row0 = blockIdx.y * 128;
    const int col0 = blockIdx.x * 128;
    const int wm = (wave >> 1) * 64;
    const int wn = (wave & 1) * 64;
    const int fr = lane & 15;   // frag row/col within 16x16
    const int kq = lane >> 4;   // k-quad (which 8 of K=32)

    const unsigned short* agp = A + (size_t)(row0 + (tid >> 2)) * KDIM + (tid & 3) * 8;
    const unsigned short* bgp = B + (size_t)(col0 + (tid >> 2)) * KDIM + (tid & 3) * 8;

    f32x4 acc[4][4] = {};

    for (int k0 = 0; k0 < KDIM; k0 += 32) {
        __builtin_amdgcn_global_load_lds(
            (const __attribute__((address_space(1))) void*)(agp),
            (__attribute__((address_space(3))) void*)(&sA[tid * 8]), 16, 0, 0);
        __builtin_amdgcn_global_load_lds(
            (const __attribute__((address_space(1))) void*)(agp + 64 * KDIM),
            (__attribute__((address_space(3))) void*)(&sA[2048 + tid * 8]), 16, 0, 0);
        __builtin_amdgcn_global_load_lds(
            (const __attribute__((address_space(1))) void*)(bgp),
            (__attribute__((address_space(3))) void*)(&sB[tid * 8]), 16, 0, 0);
        __builtin_amdgcn_global_load_lds(
            (const __attribute__((address_space(1))) void*)(bgp + 64 * KDIM),
            (__attribute__((address_space(3))) void*)(&sB[2048 + tid * 8]), 16, 0, 0);
        agp += 32; bgp += 32;
        __syncthreads();

        short8 af[4], bf[4];
#pragma unroll
        for (int i = 0; i < 4; ++i)
            af[i] = *reinterpret_cast<const short8*>(&sA[(wm + i * 16 + fr) * 32 + kq * 8]);
#pragma unroll
        for (int j = 0; j < 4; ++j)
            bf[j] = *reinterpret_cast<const short8*>(&sB[(wn + j * 16 + fr) * 32 + kq * 8]);
#pragma unroll
        for (int i = 0; i < 4; ++i)
#pragma unroll
            for (int j = 0; j < 4; ++j)
                acc[i][j] = __builtin_amdgcn_mfma_f32_16x16x32_bf16(af[i], bf[j], acc[i][j], 0, 0, 0);
        __syncthreads();
    }

    // epilogue: C/D layout col=lane&15, row=(lane>>4)*4+reg
#pragma unroll
    for (int i = 0; i < 4; ++i) {
#pragma unroll
        for (int j = 0; j < 4; ++j) {
#pragma unroll
            for (int r = 0; r < 4; ++r) {
                int row = row0 + wm + i * 16 + kq * 4 + r;
                int col = col0 + wn + j * 16 + fr;
                C[(size_t)row * NCOLS + col] = f2bf(acc[i][j][r]);
            }
        }
    }
}

// ---------------- Scan phase 1: per-chunk aggregates, interleaved (A,Y) float2
// grid (256 chunks, 4 batches) x 256 threads, 4 channels/thread via ushort4.
__global__ __launch_bounds__(256) void chunk_agg_kernel(const unsigned short* __restrict__ qkva,
                                                        float2* __restrict__ AY) {
    const int c = blockIdx.x, b = blockIdx.y;
    const int d4 = threadIdx.x;                        // quad index 0..255; d = 4*d4
    const unsigned short* base = qkva + ((size_t)b * SEQ_N + c * CHUNK_L) * NCOLS;
    float s[4] = {0.f, 0.f, 0.f, 0.f};
    float A[4] = {1.f, 1.f, 1.f, 1.f};
#pragma unroll 4
    for (int n = 0; n < CHUNK_L; ++n) {
        ushort4 kv4 = reinterpret_cast<const ushort4*>(base + (size_t)n * NCOLS + DIM)[d4];
        ushort4 av4 = reinterpret_cast<const ushort4*>(base + (size_t)n * NCOLS + 2 * DIM)[d4];
        float kv[4] = {bf2f(kv4.x), bf2f(kv4.y), bf2f(kv4.z), bf2f(kv4.w)};
        float av[4] = {bf2f(av4.x), bf2f(av4.y), bf2f(av4.z), bf2f(av4.w)};
#pragma unroll
        for (int t = 0; t < 4; ++t) {
            float a = 1.f / (1.f + __expf(-av[t]));
            s[t] = a * s[t] + kv[t];
            A[t] *= a;
        }
    }
    float4* o = reinterpret_cast<float4*>(AY + (size_t)c * NCHANNEL + b * DIM);
    float4 p0, p1;
    p0.x = A[0]; p0.y = s[0]; p0.z = A[1]; p0.w = s[1];
    p1.x = A[2]; p1.y = s[2]; p1.z = A[3]; p1.w = s[3];
    o[2 * d4]     = p0;
    o[2 * d4 + 1] = p1;
}

// ---------------- Scan phase 2: sequential scan over chunk aggregates
// 64 blocks x 64 threads (64 CUs engaged), one float2 load per link.
__global__ __launch_bounds__(64) void agg_scan_kernel(const float2* __restrict__ AY,
                                                      float* __restrict__ Sin) {
    const int ch = blockIdx.x * 64 + threadIdx.x;   // 0..4095
    float s = 0.f;
#pragma unroll 8
    for (int c = 0; c < NCHUNK; ++c) {
        Sin[(size_t)c * NCHANNEL + ch] = s;
        float2 ay = AY[(size_t)c * NCHANNEL + ch];
        s = ay.x * s + ay.y;
    }
}

// ---------------- Scan phase 3: rescan chunk with correct entry state, out = q*y
__global__ __launch_bounds__(256) void apply_kernel(const unsigned short* __restrict__ qkva,
                                                    const float* __restrict__ Sin,
                                                    float* __restrict__ out) {
    const int c = blockIdx.x, b = blockIdx.y;
    const int d4 = threadIdx.x;                        // quad index 0..255; d = 4*d4
    const unsigned short* base = qkva + ((size_t)b * SEQ_N + c * CHUNK_L) * NCOLS;
    float* obase = out + ((size_t)b * SEQ_N + c * CHUNK_L) * DIM;
    float4 s4 = reinterpret_cast<const float4*>(Sin + (size_t)c * NCHANNEL + b * DIM)[d4];
    float s[4] = {s4.x, s4.y, s4.z, s4.w};
#pragma unroll 4
    for (int n = 0; n < CHUNK_L; ++n) {
        ushort4 kv4 = reinterpret_cast<const ushort4*>(base + (size_t)n * NCOLS + DIM)[d4];
        ushort4 av4 = reinterpret_cast<const ushort4*>(base + (size_t)n * NCOLS + 2 * DIM)[d4];
        ushort4 q4  = reinterpret_cast<const ushort4*>(base + (size_t)n * NCOLS)[d4];
        float kv[4] = {bf2f(kv4.x), bf2f(kv4.y), bf2f(kv4.z), bf2f(kv4.w)};
        float av[4] = {bf2f(av4.x), bf2f(av4.y), bf2f(av4.z), bf2f(av4.w)};
        float q[4]  = {bf2f(q4.x),  bf2f(q4.y),  bf2f(q4.z),  bf2f(q4.w)};
        float4 o;
        {
            float a0 = 1.f / (1.f + __expf(-av[0])); s[0] = a0 * s[0] + kv[0]; o.x = q[0] * s[0];
            float a1 = 1.f / (1.f + __expf(-av[1])); s[1] = a1 * s[1] + kv[1]; o.y = q[1] * s[1];
            float a2 = 1.f / (1.f + __expf(-av[2])); s[2] = a2 * s[2] + kv[2]; o.z = q[2] * s[2];
            float a3 = 1.f / (1.f + __expf(-av[3])); s[3] = a3 * s[3] + kv[3]; o.w = q[3] * s[3];
        }
        reinterpret_cast<float4*>(obase + (size_t)n * DIM)[d4] = o;
    }
}

extern "C" void kernel_launch(void* const* d_in, const int* in_sizes, int n_in,
                              void* d_out, int out_size, void* d_ws, size_t ws_size,
                              hipStream_t stream) {
    const float* x     = (const float*)d_in[0];   // [4,4096,1024]
    const float* w     = (const float*)d_in[1];   // [3072,1024]
    const float* gamma = (const float*)d_in[2];   // [1024]
    float* out = (float*)d_out;                   // [4,4096,1024]

    char* ws = (char*)d_ws;
    // workspace layout (bytes):
    unsigned short* wb   = (unsigned short*)(ws);             // 3072*1024*2   = 6,291,456
    unsigned short* h    = (unsigned short*)(ws + 6291456);   // 16384*1024*2  = 33,554,432
    unsigned short* qkva = (unsigned short*)(ws + 39845888);  // 16384*3072*2  = 100,663,296
    // Scan temporaries live inside h's region — h is dead after the GEMM.
    float2* AY  = (float2*)(ws + 6291456);                    // 256*4096*8 = 8,388,608
    float*  Sin = (float*)(ws + 6291456 + 8388608);           // 256*4096*4 = 4,194,304
    // total ws: 140,509,184 bytes

    prep_kernel<<<4096 + 3072, 256, 0, stream>>>(x, gamma, h, w, wb);
    gemm_bt_kernel<<<dim3(NCOLS / 128, M_ROWS / 128), 256, 0, stream>>>(h, wb, qkva);
    chunk_agg_kernel<<<dim3(NCHUNK, BATCH), 256, 0, stream>>>(qkva, AY);
    agg_scan_kernel<<<NCHANNEL / 64, 64, 0, stream>>>(AY, Sin);
    apply_kernel<<<dim3(NCHUNK, BATCH), 256, 0, stream>>>(qkva, Sin, out);
}